// Round 5
// baseline (551.220 us; speedup 1.0000x reference)
//
#include <hip/hip_runtime.h>
#include <math.h>

#define BBATCH 8
#define TSEQ   2048
#define EDIM   384
#define NHEAD  6
#define DHEAD  64
#define NBH    48
#define QTILE  128
#define NQT    16
#define NW1    442368          // 3*6*64*384
#define NW2    147456          // 384*384
#define XSZ    6291456         // B*T*E
#define KVSZ   6291456         // NBH*T*HS
#define NSLOT  40              // kv-chunk slots per (bh) across all qt

typedef __attribute__((ext_vector_type(8)))  short bf16x8;
typedef __attribute__((ext_vector_type(16))) float f32x16;
typedef __attribute__((ext_vector_type(2)))  int   i32x2;
typedef unsigned short u16;
typedef unsigned int   u32;

#define MFMA(a, b, c) __builtin_amdgcn_mfma_f32_32x32x16_bf16(a, b, c, 0, 0, 0)

__device__ __forceinline__ u16 f2bf(float f) {
  u32 u = __float_as_uint(f);
  return (u16)((u + 0x7fffu + ((u >> 16) & 1u)) >> 16);
}
__device__ __forceinline__ float bf2f(u16 h) {
  return __uint_as_float(((u32)h) << 16);
}
__device__ __forceinline__ bf16x8 mk8(u32 w0, u32 w1, u32 w2, u32 w3) {
  union { u32 u[4]; bf16x8 v; } t;
  t.u[0] = w0; t.u[1] = w1; t.u[2] = w2; t.u[3] = w3;
  return t.v;
}

// chunk tables: slots sorted heavy-first; chunk c covers tiles [8c, min(8c+8, 2qt+2))
__device__ const unsigned char SLOT_QT[NSLOT] = {
  3,4,5,6,7,7,8,8,9,9,10,10,11,11,11,12,12,12,13,13,13,14,14,14,15,15,15,15,
  2,6,10,14, 1,5,9,13, 0,4,8,12};
__device__ const unsigned char SLOT_C[NSLOT] = {
  0,0,0,0,0,1,0,1,0,1,0,1,0,1,2,0,1,2,0,1,2,0,1,2,0,1,2,3,
  0,1,2,3, 0,1,2,3, 0,1,2,3};

// ---------------- kernel 0a: weight prep (transpose + hi/lo split) -----------
__global__ __launch_bounds__(256) void prep_w_k(
    const float* __restrict__ Wq, const float* __restrict__ Wk,
    const float* __restrict__ Wv, const float* __restrict__ Wo,
    u16* __restrict__ wtH, u16* __restrict__ wtL,
    u16* __restrict__ woH, u16* __restrict__ woL) {
  int idx = blockIdx.x * 256 + threadIdx.x;
  if (idx < NW1) {
    int d = idx & 63;
    int q = idx >> 6;
    int e = q % EDIM;
    int ph = q / EDIM;
    const float* W = (ph < 6) ? Wq : (ph < 12) ? Wk : Wv;
    int h = ph % 6;
    float v = W[((size_t)h * EDIM + e) * DHEAD + d];
    u16 hi = f2bf(v);
    size_t o = ((size_t)ph * DHEAD + d) * EDIM + e;
    wtH[o] = hi;
    wtL[o] = f2bf(v - bf2f(hi));
  } else {
    int o = idx - NW1;
    int eo = o % EDIM;
    int hd = o / EDIM;
    float v = Wo[(size_t)hd * EDIM + eo];
    u16 hi = f2bf(v);
    size_t oo = (size_t)eo * EDIM + hd;
    woH[oo] = hi;
    woL[oo] = f2bf(v - bf2f(hi));
  }
}

// ---------------- kernel 0b: pre-split x into bf16 hi/lo ---------------------
__global__ __launch_bounds__(256) void splitx_k(
    const float* __restrict__ x, u16* __restrict__ xh, u16* __restrict__ xl) {
  int i = (blockIdx.x * 256 + threadIdx.x) * 8;
  float4 a = *(const float4*)(x + i);
  float4 b = *(const float4*)(x + i + 4);
  u16 h0 = f2bf(a.x), h1 = f2bf(a.y), h2 = f2bf(a.z), h3 = f2bf(a.w);
  u16 h4 = f2bf(b.x), h5 = f2bf(b.y), h6 = f2bf(b.z), h7 = f2bf(b.w);
  uint4 H, L;
  H.x = (u32)h0 | ((u32)h1 << 16); H.y = (u32)h2 | ((u32)h3 << 16);
  H.z = (u32)h4 | ((u32)h5 << 16); H.w = (u32)h6 | ((u32)h7 << 16);
  L.x = (u32)f2bf(a.x - bf2f(h0)) | ((u32)f2bf(a.y - bf2f(h1)) << 16);
  L.y = (u32)f2bf(a.z - bf2f(h2)) | ((u32)f2bf(a.w - bf2f(h3)) << 16);
  L.z = (u32)f2bf(b.x - bf2f(h4)) | ((u32)f2bf(b.y - bf2f(h5)) << 16);
  L.w = (u32)f2bf(b.z - bf2f(h6)) | ((u32)f2bf(b.w - bf2f(h7)) << 16);
  *(uint4*)(xh + i) = H;
  *(uint4*)(xl + i) = L;
}

// ---------------- kernel 1: Q/K/V projection (split-bf16 MFMA) ---------------
// V path additionally emits psum[bh][tile][d] = sum over the 128 rows (fp32).
__global__ __launch_bounds__(256, 2) void proj_k(
    const u16* __restrict__ xh, const u16* __restrict__ xl,
    const u16* __restrict__ wtH, const u16* __restrict__ wtL,
    u16* __restrict__ qh, u16* __restrict__ ql,
    u16* __restrict__ kh, u16* __restrict__ kl,
    u16* __restrict__ vTh, u16* __restrict__ vTl,
    float* __restrict__ psum) {
  __shared__ __align__(16) unsigned char sm[32768];
  const int tid = threadIdx.x;
  const int w = tid >> 6, l = tid & 63, lh = l >> 5, l31 = l & 31;
  const int gid = ((blockIdx.x & 7) * 288) + ((int)blockIdx.x >> 3);
  const int bx = gid / 18, ph = gid % 18;
  const int p = ph / 6, h = ph % 6;
  const int bt0 = bx * 128;
  const u16* __restrict__ wBh = wtH + (size_t)ph * DHEAD * EDIM;
  const u16* __restrict__ wBl = wtL + (size_t)ph * DHEAD * EDIM;

  f32x16 acc0, acc1;
#pragma unroll
  for (int i = 0; i < 16; ++i) { acc0[i] = 0.f; acc1[i] = 0.f; }

  for (int k0 = 0; k0 < EDIM; k0 += 64) {
    __syncthreads();
#pragma unroll
    for (int i = 0; i < 4; ++i) {
      int c = tid + i * 256;
      int r = c >> 3, s = c & 7;
      int off = (r * 128 + s * 16) ^ ((r & 7) << 4);
      size_t g = (size_t)(bt0 + r) * EDIM + k0 + s * 8;
      *(uint4*)(sm + off) = *(const uint4*)(xh + g);
      *(uint4*)(sm + 16384 + off) = *(const uint4*)(xl + g);
    }
    __syncthreads();
    const int arow = 32 * w + l31;
#pragma unroll
    for (int ks = 0; ks < 4; ++ks) {
      int aoff = (arow * 128 + ks * 32 + 16 * lh) ^ ((arow & 7) << 4);
      bf16x8 aH = *(const bf16x8*)(sm + aoff);
      bf16x8 aL = *(const bf16x8*)(sm + 16384 + aoff);
      int eoff = k0 + ks * 16 + 8 * lh;
      size_t b0 = (size_t)l31 * EDIM + eoff;
      size_t b1 = (size_t)(32 + l31) * EDIM + eoff;
      bf16x8 bH0 = *(const bf16x8*)(wBh + b0);
      bf16x8 bL0 = *(const bf16x8*)(wBl + b0);
      bf16x8 bH1 = *(const bf16x8*)(wBh + b1);
      bf16x8 bL1 = *(const bf16x8*)(wBl + b1);
      acc0 = MFMA(aH, bH0, acc0); acc0 = MFMA(aH, bL0, acc0); acc0 = MFMA(aL, bH0, acc0);
      acc1 = MFMA(aH, bH1, acc1); acc1 = MFMA(aH, bL1, acc1); acc1 = MFMA(aL, bH1, acc1);
    }
  }

  const int b = bt0 >> 11, t0b = bt0 & (TSEQ - 1);
  const int bh = b * NHEAD + h;
  const float scale = (p == 0) ? 0.125f : 1.0f;

  if (p < 2) {
    u16* oH = (p == 0) ? qh : kh;
    u16* oL = (p == 0) ? ql : kl;
#pragma unroll
    for (int reg = 0; reg < 16; ++reg) {
      int row = (reg & 3) + 8 * (reg >> 2) + 4 * lh + 32 * w;
      size_t base = ((size_t)bh * TSEQ + t0b + row) * DHEAD;
      float v0 = acc0[reg] * scale, v1 = acc1[reg] * scale;
      u16 h0 = f2bf(v0), h1 = f2bf(v1);
      oH[base + l31] = h0;       oL[base + l31] = f2bf(v0 - bf2f(h0));
      oH[base + 32 + l31] = h1;  oL[base + 32 + l31] = f2bf(v1 - bf2f(h1));
    }
  } else {
    // V: transpose via LDS -> vT[bh][d][t]
    u16* T = (u16*)sm;
#pragma unroll
    for (int half = 0; half < 2; ++half) {
      __syncthreads();
#pragma unroll
      for (int reg = 0; reg < 16; ++reg) {
        int t = (reg & 3) + 8 * (reg >> 2) + 4 * lh + 32 * w;
        float v0 = acc0[reg], v1 = acc1[reg];
        u16 e0, e1;
        if (half == 0) { e0 = f2bf(v0); e1 = f2bf(v1); }
        else {
          u16 a0 = f2bf(v0), a1 = f2bf(v1);
          e0 = f2bf(v0 - bf2f(a0)); e1 = f2bf(v1 - bf2f(a1));
        }
        T[l31 * 132 + t] = e0;
        T[(32 + l31) * 132 + t] = e1;
      }
      __syncthreads();
      u16* dst = half ? vTl : vTh;
#pragma unroll
      for (int i = 0; i < 8; ++i) {
        int c = tid + i * 256;
        int d = c >> 5, s = c & 31;
        uint2 val = *(const uint2*)(T + d * 132 + s * 4);
        *(uint2*)(dst + ((size_t)bh * DHEAD + d) * TSEQ + t0b + s * 4) = val;
      }
    }
    // per-tile V column sums (fp32, pre-split) for the masked-tail closed form
    float s0 = 0.f, s1 = 0.f;
#pragma unroll
    for (int reg = 0; reg < 16; ++reg) { s0 += acc0[reg]; s1 += acc1[reg]; }
    s0 += __shfl_xor(s0, 32);
    s1 += __shfl_xor(s1, 32);
    __syncthreads();
    float* ps = (float*)sm;
    if (lh == 0) { ps[w * 64 + l31] = s0; ps[w * 64 + 32 + l31] = s1; }
    __syncthreads();
    if (tid < 64) {
      float t = ps[tid] + ps[64 + tid] + ps[128 + tid] + ps[192 + tid];
      int tile = t0b >> 7;
      psum[((size_t)bh * NQT + tile) * DHEAD + tid] = t;
    }
  }
}

// ---------------- kernel 2: flash attention, chunked KV-split ----------------
// grid 1920 XCD-chunked -> (bh, slot); slot -> (qt, chunk). Each block: 128 q
// rows, <=8 KV tiles of 64. No online max (multiplicative mask => logits ~N(0,1),
// static max 0); partials are additive -> atomicAdd into pO/pl.
__global__ __launch_bounds__(256, 4) void attn_k(
    const u16* __restrict__ qh, const u16* __restrict__ ql,
    const u16* __restrict__ kh, const u16* __restrict__ kl,
    const u16* __restrict__ vTh, const u16* __restrict__ vTl,
    float* __restrict__ pO, float* __restrict__ pl) {
  __shared__ __align__(16) unsigned char sm[32768];
  const int oKl = 8192, oVh = 16384, oVl = 24576;
  const int tid = threadIdx.x;
  const int w = tid >> 6, l = tid & 63, lh = l >> 5, l31 = l & 31;
  const int gid = ((blockIdx.x & 7) * 240) + ((int)blockIdx.x >> 3);
  const int bh = gid / NSLOT, slot = gid % NSLOT;
  const int qt = SLOT_QT[slot], cch = SLOT_C[slot];
  const int tbeg = cch * 8;
  const int tend = min(cch * 8 + 8, 2 * qt + 2);
  const int t0 = qt * QTILE;
  const size_t kvb = (size_t)bh * TSEQ * DHEAD;

  // ---- stage Q (hi at 0, lo at 16384), swizzled
#pragma unroll
  for (int i = 0; i < 4; ++i) {
    int c = tid + i * 256;
    int r = c >> 3, s = c & 7;
    int off = (r * 128 + s * 16) ^ ((r & 7) << 4);
    size_t g = kvb + (size_t)(t0 + r) * DHEAD + s * 8;
    *(uint4*)(sm + off) = *(const uint4*)(qh + g);
    *(uint4*)(sm + 16384 + off) = *(const uint4*)(ql + g);
  }
  __syncthreads();
  bf16x8 qfH[4], qfL[4];
  {
    const int qrow = 32 * w + l31;
#pragma unroll
    for (int ks = 0; ks < 4; ++ks) {
      int off = (qrow * 128 + ks * 32 + 16 * lh) ^ ((qrow & 7) << 4);
      qfH[ks] = *(const bf16x8*)(sm + off);
      qfL[ks] = *(const bf16x8*)(sm + 16384 + off);
    }
  }
  // prefetch first tile
  uint4 kpH[2], kpL[2], vpH[2], vpL[2];
#pragma unroll
  for (int i = 0; i < 2; ++i) {
    int c = tid + i * 256;
    int r = c >> 3, s = c & 7;
    int j0 = tbeg * 64;
    kpH[i] = *(const uint4*)(kh + kvb + (size_t)(j0 + r) * DHEAD + s * 8);
    kpL[i] = *(const uint4*)(kl + kvb + (size_t)(j0 + r) * DHEAD + s * 8);
    vpH[i] = *(const uint4*)(vTh + kvb + (size_t)r * TSEQ + j0 + s * 8);
    vpL[i] = *(const uint4*)(vTl + kvb + (size_t)r * TSEQ + j0 + s * 8);
  }
  __syncthreads();   // Q frags extracted; LDS reusable

  f32x16 accO0, accO1;
#pragma unroll
  for (int i = 0; i < 16; ++i) { accO0[i] = 0.f; accO1[i] = 0.f; }
  float lrun = 0.f;
  const int qg = t0 + 32 * w + l31;

  for (int jt = tbeg; jt < tend; ++jt) {
#pragma unroll
    for (int i = 0; i < 2; ++i) {
      int c = tid + i * 256;
      int r = c >> 3, s = c & 7;
      int off = (r * 128 + s * 16) ^ ((r & 7) << 4);
      *(uint4*)(sm + off) = kpH[i];
      *(uint4*)(sm + oKl + off) = kpL[i];
      *(uint4*)(sm + oVh + off) = vpH[i];
      *(uint4*)(sm + oVl + off) = vpL[i];
    }
    __syncthreads();
    if (jt + 1 < tend) {
      int j0 = (jt + 1) * 64;
#pragma unroll
      for (int i = 0; i < 2; ++i) {
        int c = tid + i * 256;
        int r = c >> 3, s = c & 7;
        kpH[i] = *(const uint4*)(kh + kvb + (size_t)(j0 + r) * DHEAD + s * 8);
        kpL[i] = *(const uint4*)(kl + kvb + (size_t)(j0 + r) * DHEAD + s * 8);
        vpH[i] = *(const uint4*)(vTh + kvb + (size_t)r * TSEQ + j0 + s * 8);
        vpL[i] = *(const uint4*)(vTl + kvb + (size_t)r * TSEQ + j0 + s * 8);
      }
    }
#pragma unroll
    for (int jh = 0; jh < 2; ++jh) {
      f32x16 accS;
#pragma unroll
      for (int i = 0; i < 16; ++i) accS[i] = 0.f;
      const int krow = jh * 32 + l31;
      const int ksw = (l31 & 7) << 4;
      __builtin_amdgcn_s_setprio(1);
#pragma unroll
      for (int ks = 0; ks < 4; ++ks) {
        int koff = (krow * 128 + ks * 32 + 16 * lh) ^ ksw;
        bf16x8 aH = *(const bf16x8*)(sm + koff);
        bf16x8 aL = *(const bf16x8*)(sm + oKl + koff);
        accS = MFMA(aH, qfH[ks], accS);
        accS = MFMA(aH, qfL[ks], accS);
        accS = MFMA(aL, qfH[ks], accS);
      }
      __builtin_amdgcn_s_setprio(0);
      const int jb = jt * 64 + jh * 32 + 4 * lh;
      float ps = 0.f;
#pragma unroll
      for (int ml = 0; ml < 2; ++ml) {
        int rb = ml * 8;
        u32 hw[4], lw[4];
#pragma unroll
        for (int pr = 0; pr < 4; ++pr) {
          int r0 = rb + 2 * pr;
          int jg0 = jb + (r0 & 3) + 8 * (r0 >> 2);
          float s0 = (jg0 > qg) ? 0.f : accS[r0];
          float s1 = ((jg0 + 1) > qg) ? 0.f : accS[r0 + 1];
          float p0 = __expf(s0), p1 = __expf(s1);
          ps += p0 + p1;
          u16 a0 = f2bf(p0), a1 = f2bf(p1);
          hw[pr] = (u32)a0 | ((u32)a1 << 16);
          lw[pr] = (u32)f2bf(p0 - bf2f(a0)) | ((u32)f2bf(p1 - bf2f(a1)) << 16);
        }
        i32x2 s1 = __builtin_amdgcn_permlane32_swap((int)hw[0], (int)hw[2], false, false);
        i32x2 s2 = __builtin_amdgcn_permlane32_swap((int)hw[1], (int)hw[3], false, false);
        bf16x8 pH = mk8((u32)s1.x, (u32)s2.x, (u32)s1.y, (u32)s2.y);
        i32x2 t1 = __builtin_amdgcn_permlane32_swap((int)lw[0], (int)lw[2], false, false);
        i32x2 t2 = __builtin_amdgcn_permlane32_swap((int)lw[1], (int)lw[3], false, false);
        bf16x8 pL = mk8((u32)t1.x, (u32)t2.x, (u32)t1.y, (u32)t2.y);
        int m = jh * 2 + ml;
        int vo0 = (l31 * 128 + m * 32 + 16 * lh) ^ ksw;
        int vo1 = ((32 + l31) * 128 + m * 32 + 16 * lh) ^ ksw;
        bf16x8 vH0 = *(const bf16x8*)(sm + oVh + vo0);
        bf16x8 vL0 = *(const bf16x8*)(sm + oVl + vo0);
        bf16x8 vH1 = *(const bf16x8*)(sm + oVh + vo1);
        bf16x8 vL1 = *(const bf16x8*)(sm + oVl + vo1);
        __builtin_amdgcn_s_setprio(1);
        accO0 = MFMA(pH, vH0, accO0); accO0 = MFMA(pH, vL0, accO0); accO0 = MFMA(pL, vH0, accO0);
        accO1 = MFMA(pH, vH1, accO1); accO1 = MFMA(pH, vL1, accO1); accO1 = MFMA(pL, vH1, accO1);
        __builtin_amdgcn_s_setprio(0);
      }
      lrun += ps;
    }
    __syncthreads();
  }

  // ---- accumulate partials (additive: no max-rescale in this softmax)
  lrun += __shfl_xor(lrun, 32);
  const size_t slotO = ((size_t)bh * NQT + qt);
  if (lh == 0)
    atomicAdd(&pl[slotO * 128 + 32 * w + l31], lrun);
  float* po = pO + slotO * 8192;
#pragma unroll
  for (int reg = 0; reg < 16; ++reg) {
    int r = (reg & 3) + 8 * (reg >> 2) + 4 * lh + 32 * w;
    atomicAdd(&po[r * 64 + l31], accO0[reg]);
    atomicAdd(&po[r * 64 + 32 + l31], accO1[reg]);
  }
}

// ---------------- kernel 3: combine partials + masked tail + normalize -------
// grid 768: (bh, qt). tail: (2048-(qt+1)*128) zero-logit entries, weight 1 each;
// numerator tail = suffix of per-tile V sums (psum).
__global__ __launch_bounds__(256) void combine_k(
    const float* __restrict__ pO, const float* __restrict__ pl,
    const float* __restrict__ psum,
    u16* __restrict__ cxh, u16* __restrict__ cxl) {
  const int bid = blockIdx.x;
  const int bh = bid >> 4, qt = bid & 15;
  const int b = bh / NHEAD, h = bh % NHEAD;
  const int tid = threadIdx.x;
  const int d = tid & 63, rg = tid >> 6;
  float tail = 0.f;
  for (int tt = qt + 1; tt < NQT; ++tt)
    tail += psum[((size_t)bh * NQT + tt) * DHEAD + d];
  const float tcnt = (float)(TSEQ - (qt + 1) * 128);
  const float* po = pO + (size_t)bid * 8192;
  const float* plp = pl + (size_t)bid * 128;
#pragma unroll 4
  for (int k = 0; k < 32; ++k) {
    int r = rg * 32 + k;
    float inv = 1.0f / (plp[r] + tcnt);
    float v = (po[r * 64 + d] + tail) * inv;
    u16 hbits = f2bf(v);
    size_t o = ((size_t)b * TSEQ + qt * 128 + r) * EDIM + h * DHEAD + d;
    cxh[o] = hbits;
    cxl[o] = f2bf(v - bf2f(hbits));
  }
}

// ---------------- kernel 4: output projection --------------------------------
__global__ __launch_bounds__(256, 2) void outproj_k(
    const u16* __restrict__ cxh, const u16* __restrict__ cxl,
    const u16* __restrict__ woH, const u16* __restrict__ woL,
    float* __restrict__ out) {
  __shared__ __align__(16) unsigned char sm[32768];
  const int tid = threadIdx.x;
  const int w = tid >> 6, l = tid & 63, lh = l >> 5, l31 = l & 31;
  const int gid = ((blockIdx.x & 7) * 96) + ((int)blockIdx.x >> 3);
  const int bx = gid / 6, ey = gid % 6;
  const int bt0 = bx * 128, e0 = ey * 64;

  f32x16 acc0, acc1;
#pragma unroll
  for (int i = 0; i < 16; ++i) { acc0[i] = 0.f; acc1[i] = 0.f; }

  for (int k0 = 0; k0 < EDIM; k0 += 64) {
    __syncthreads();
#pragma unroll
    for (int i = 0; i < 4; ++i) {
      int c = tid + i * 256;
      int r = c >> 3, s = c & 7;
      int off = (r * 128 + s * 16) ^ ((r & 7) << 4);
      size_t g = (size_t)(bt0 + r) * EDIM + k0 + s * 8;
      *(uint4*)(sm + off) = *(const uint4*)(cxh + g);
      *(uint4*)(sm + 16384 + off) = *(const uint4*)(cxl + g);
    }
    __syncthreads();
    const int arow = 32 * w + l31;
#pragma unroll
    for (int ks = 0; ks < 4; ++ks) {
      int aoff = (arow * 128 + ks * 32 + 16 * lh) ^ ((arow & 7) << 4);
      bf16x8 aH = *(const bf16x8*)(sm + aoff);
      bf16x8 aL = *(const bf16x8*)(sm + 16384 + aoff);
      int hdoff = k0 + ks * 16 + 8 * lh;
      size_t b0 = (size_t)(e0 + l31) * EDIM + hdoff;
      size_t b1 = (size_t)(e0 + 32 + l31) * EDIM + hdoff;
      bf16x8 bH0 = *(const bf16x8*)(woH + b0);
      bf16x8 bL0 = *(const bf16x8*)(woL + b0);
      bf16x8 bH1 = *(const bf16x8*)(woH + b1);
      bf16x8 bL1 = *(const bf16x8*)(woL + b1);
      acc0 = MFMA(aH, bH0, acc0); acc0 = MFMA(aH, bL0, acc0); acc0 = MFMA(aL, bH0, acc0);
      acc1 = MFMA(aH, bH1, acc1); acc1 = MFMA(aH, bL1, acc1); acc1 = MFMA(aL, bH1, acc1);
    }
  }
#pragma unroll
  for (int reg = 0; reg < 16; ++reg) {
    int row = (reg & 3) + 8 * (reg >> 2) + 4 * lh + 32 * w;
    size_t o = (size_t)(bt0 + row) * EDIM + e0;
    out[o + l31] = acc0[reg];
    out[o + 32 + l31] = acc1[reg];
  }
}

// ---------------- launch -----------------------------------------------------
extern "C" void kernel_launch(void* const* d_in, const int* in_sizes, int n_in,
                              void* d_out, int out_size, void* d_ws, size_t ws_size,
                              hipStream_t stream) {
  (void)in_sizes; (void)n_in; (void)out_size; (void)ws_size;
  const float* x  = (const float*)d_in[0];
  const float* Wq = (const float*)d_in[1];
  const float* Wk = (const float*)d_in[2];
  const float* Wv = (const float*)d_in[3];
  const float* Wo = (const float*)d_in[4];
  float* out = (float*)d_out;

  // workspace carve (~129 MB)
  u16* qh  = (u16*)d_ws;
  u16* ql  = qh + KVSZ;
  u16* kh  = ql + KVSZ;
  u16* kl  = kh + KVSZ;
  u16* vTh = kl + KVSZ;
  u16* vTl = vTh + KVSZ;
  u16* xh  = vTl + KVSZ;
  u16* xl  = xh + XSZ;
  u16* wtH = xl + XSZ;
  u16* wtL = wtH + NW1;
  u16* woH = wtL + NW1;
  u16* woL = woH + NW2;
  float* psum = (float*)(woL + NW2);                 // 48*16*64
  float* pO   = psum + (size_t)NBH * NQT * DHEAD;    // 48*16*128*64
  float* pl   = pO + (size_t)NBH * NQT * 128 * 64;   // 48*16*128
  u16* cxh = xh;   // alias: x dead after proj
  u16* cxl = xl;

  hipMemsetAsync(pO, 0, ((size_t)NBH * NQT * 128 * 65) * sizeof(float), stream);
  hipLaunchKernelGGL(prep_w_k, dim3((NW1 + NW2) / 256), dim3(256), 0, stream,
                     Wq, Wk, Wv, Wo, wtH, wtL, woH, woL);
  hipLaunchKernelGGL(splitx_k, dim3(XSZ / 2048), dim3(256), 0, stream, x, xh, xl);
  hipLaunchKernelGGL(proj_k, dim3(2304), dim3(256), 0, stream,
                     xh, xl, wtH, wtL, qh, ql, kh, kl, vTh, vTl, psum);
  hipLaunchKernelGGL(attn_k, dim3(1920), dim3(256), 0, stream,
                     qh, ql, kh, kl, vTh, vTl, pO, pl);
  hipLaunchKernelGGL(combine_k, dim3(NBH * NQT), dim3(256), 0, stream,
                     pO, pl, psum, cxh, cxl);
  hipLaunchKernelGGL(outproj_k, dim3(768), dim3(256), 0, stream,
                     cxh, cxl, woH, woL, out);
}

// Round 6
// 460.618 us; speedup vs baseline: 1.1967x; 1.1967x over previous
//
#include <hip/hip_runtime.h>
#include <math.h>

#define BBATCH 8
#define TSEQ   2048
#define EDIM   384
#define NHEAD  6
#define DHEAD  64
#define NBH    48
#define QTILE  128
#define NQT    16
#define NW1    442368          // 3*6*64*384
#define NW2    147456          // 384*384
#define XSZ    6291456         // B*T*E
#define KVSZ   6291456         // NBH*T*HS

typedef __attribute__((ext_vector_type(8)))  short bf16x8;
typedef __attribute__((ext_vector_type(16))) float f32x16;
typedef __attribute__((ext_vector_type(2)))  int   i32x2;
typedef unsigned short u16;
typedef unsigned int   u32;

#define MFMA(a, b, c) __builtin_amdgcn_mfma_f32_32x32x16_bf16(a, b, c, 0, 0, 0)

__device__ __forceinline__ u16 f2bf(float f) {
  u32 u = __float_as_uint(f);
  return (u16)((u + 0x7fffu + ((u >> 16) & 1u)) >> 16);
}
__device__ __forceinline__ float bf2f(u16 h) {
  return __uint_as_float(((u32)h) << 16);
}
__device__ __forceinline__ bf16x8 mk8(u32 w0, u32 w1, u32 w2, u32 w3) {
  union { u32 u[4]; bf16x8 v; } t;
  t.u[0] = w0; t.u[1] = w1; t.u[2] = w2; t.u[3] = w3;
  return t.v;
}

// ---------------- kernel 0a: weight prep (transpose + hi/lo split) -----------
__global__ __launch_bounds__(256) void prep_w_k(
    const float* __restrict__ Wq, const float* __restrict__ Wk,
    const float* __restrict__ Wv, const float* __restrict__ Wo,
    u16* __restrict__ wtH, u16* __restrict__ wtL,
    u16* __restrict__ woH, u16* __restrict__ woL) {
  int idx = blockIdx.x * 256 + threadIdx.x;
  if (idx < NW1) {
    int d = idx & 63;
    int q = idx >> 6;
    int e = q % EDIM;
    int ph = q / EDIM;
    const float* W = (ph < 6) ? Wq : (ph < 12) ? Wk : Wv;
    int h = ph % 6;
    float v = W[((size_t)h * EDIM + e) * DHEAD + d];
    u16 hi = f2bf(v);
    size_t o = ((size_t)ph * DHEAD + d) * EDIM + e;
    wtH[o] = hi;
    wtL[o] = f2bf(v - bf2f(hi));
  } else {
    int o = idx - NW1;
    int eo = o % EDIM;
    int hd = o / EDIM;
    float v = Wo[(size_t)hd * EDIM + eo];
    u16 hi = f2bf(v);
    size_t oo = (size_t)eo * EDIM + hd;
    woH[oo] = hi;
    woL[oo] = f2bf(v - bf2f(hi));
  }
}

// ---------------- kernel 0b: pre-split x into bf16 hi/lo ---------------------
__global__ __launch_bounds__(256) void splitx_k(
    const float* __restrict__ x, u16* __restrict__ xh, u16* __restrict__ xl) {
  int i = (blockIdx.x * 256 + threadIdx.x) * 8;
  float4 a = *(const float4*)(x + i);
  float4 b = *(const float4*)(x + i + 4);
  u16 h0 = f2bf(a.x), h1 = f2bf(a.y), h2 = f2bf(a.z), h3 = f2bf(a.w);
  u16 h4 = f2bf(b.x), h5 = f2bf(b.y), h6 = f2bf(b.z), h7 = f2bf(b.w);
  uint4 H, L;
  H.x = (u32)h0 | ((u32)h1 << 16); H.y = (u32)h2 | ((u32)h3 << 16);
  H.z = (u32)h4 | ((u32)h5 << 16); H.w = (u32)h6 | ((u32)h7 << 16);
  L.x = (u32)f2bf(a.x - bf2f(h0)) | ((u32)f2bf(a.y - bf2f(h1)) << 16);
  L.y = (u32)f2bf(a.z - bf2f(h2)) | ((u32)f2bf(a.w - bf2f(h3)) << 16);
  L.z = (u32)f2bf(b.x - bf2f(h4)) | ((u32)f2bf(b.y - bf2f(h5)) << 16);
  L.w = (u32)f2bf(b.z - bf2f(h6)) | ((u32)f2bf(b.w - bf2f(h7)) << 16);
  *(uint4*)(xh + i) = H;
  *(uint4*)(xl + i) = L;
}

// ---------------- kernel 1: Q/K/V projection (split-bf16 MFMA) ---------------
// V path additionally emits psum[bh][tile][d] = sum over the 128 rows (fp32).
__global__ __launch_bounds__(256, 2) void proj_k(
    const u16* __restrict__ xh, const u16* __restrict__ xl,
    const u16* __restrict__ wtH, const u16* __restrict__ wtL,
    u16* __restrict__ qh, u16* __restrict__ ql,
    u16* __restrict__ kh, u16* __restrict__ kl,
    u16* __restrict__ vTh, u16* __restrict__ vTl,
    float* __restrict__ psum) {
  __shared__ __align__(16) unsigned char sm[32768];
  const int tid = threadIdx.x;
  const int w = tid >> 6, l = tid & 63, lh = l >> 5, l31 = l & 31;
  const int gid = ((blockIdx.x & 7) * 288) + ((int)blockIdx.x >> 3);
  const int bx = gid / 18, ph = gid % 18;
  const int p = ph / 6, h = ph % 6;
  const int bt0 = bx * 128;
  const u16* __restrict__ wBh = wtH + (size_t)ph * DHEAD * EDIM;
  const u16* __restrict__ wBl = wtL + (size_t)ph * DHEAD * EDIM;

  f32x16 acc0, acc1;
#pragma unroll
  for (int i = 0; i < 16; ++i) { acc0[i] = 0.f; acc1[i] = 0.f; }

  for (int k0 = 0; k0 < EDIM; k0 += 64) {
    __syncthreads();
#pragma unroll
    for (int i = 0; i < 4; ++i) {
      int c = tid + i * 256;
      int r = c >> 3, s = c & 7;
      int off = (r * 128 + s * 16) ^ ((r & 7) << 4);
      size_t g = (size_t)(bt0 + r) * EDIM + k0 + s * 8;
      *(uint4*)(sm + off) = *(const uint4*)(xh + g);
      *(uint4*)(sm + 16384 + off) = *(const uint4*)(xl + g);
    }
    __syncthreads();
    const int arow = 32 * w + l31;
#pragma unroll
    for (int ks = 0; ks < 4; ++ks) {
      int aoff = (arow * 128 + ks * 32 + 16 * lh) ^ ((arow & 7) << 4);
      bf16x8 aH = *(const bf16x8*)(sm + aoff);
      bf16x8 aL = *(const bf16x8*)(sm + 16384 + aoff);
      int eoff = k0 + ks * 16 + 8 * lh;
      size_t b0 = (size_t)l31 * EDIM + eoff;
      size_t b1 = (size_t)(32 + l31) * EDIM + eoff;
      bf16x8 bH0 = *(const bf16x8*)(wBh + b0);
      bf16x8 bL0 = *(const bf16x8*)(wBl + b0);
      bf16x8 bH1 = *(const bf16x8*)(wBh + b1);
      bf16x8 bL1 = *(const bf16x8*)(wBl + b1);
      acc0 = MFMA(aH, bH0, acc0); acc0 = MFMA(aH, bL0, acc0); acc0 = MFMA(aL, bH0, acc0);
      acc1 = MFMA(aH, bH1, acc1); acc1 = MFMA(aH, bL1, acc1); acc1 = MFMA(aL, bH1, acc1);
    }
  }

  const int b = bt0 >> 11, t0b = bt0 & (TSEQ - 1);
  const int bh = b * NHEAD + h;
  const float scale = (p == 0) ? 0.125f : 1.0f;

  if (p < 2) {
    u16* oH = (p == 0) ? qh : kh;
    u16* oL = (p == 0) ? ql : kl;
#pragma unroll
    for (int reg = 0; reg < 16; ++reg) {
      int row = (reg & 3) + 8 * (reg >> 2) + 4 * lh + 32 * w;
      size_t base = ((size_t)bh * TSEQ + t0b + row) * DHEAD;
      float v0 = acc0[reg] * scale, v1 = acc1[reg] * scale;
      u16 h0 = f2bf(v0), h1 = f2bf(v1);
      oH[base + l31] = h0;       oL[base + l31] = f2bf(v0 - bf2f(h0));
      oH[base + 32 + l31] = h1;  oL[base + 32 + l31] = f2bf(v1 - bf2f(h1));
    }
  } else {
    // V: transpose via LDS -> vT[bh][d][t]
    u16* T = (u16*)sm;
#pragma unroll
    for (int half = 0; half < 2; ++half) {
      __syncthreads();
#pragma unroll
      for (int reg = 0; reg < 16; ++reg) {
        int t = (reg & 3) + 8 * (reg >> 2) + 4 * lh + 32 * w;
        float v0 = acc0[reg], v1 = acc1[reg];
        u16 e0, e1;
        if (half == 0) { e0 = f2bf(v0); e1 = f2bf(v1); }
        else {
          u16 a0 = f2bf(v0), a1 = f2bf(v1);
          e0 = f2bf(v0 - bf2f(a0)); e1 = f2bf(v1 - bf2f(a1));
        }
        T[l31 * 132 + t] = e0;
        T[(32 + l31) * 132 + t] = e1;
      }
      __syncthreads();
      u16* dst = half ? vTl : vTh;
#pragma unroll
      for (int i = 0; i < 8; ++i) {
        int c = tid + i * 256;
        int d = c >> 5, s = c & 31;
        uint2 val = *(const uint2*)(T + d * 132 + s * 4);
        *(uint2*)(dst + ((size_t)bh * DHEAD + d) * TSEQ + t0b + s * 4) = val;
      }
    }
    // per-tile V column sums (fp32) for the masked-tail closed form
    float s0 = 0.f, s1 = 0.f;
#pragma unroll
    for (int reg = 0; reg < 16; ++reg) { s0 += acc0[reg]; s1 += acc1[reg]; }
    s0 += __shfl_xor(s0, 32);
    s1 += __shfl_xor(s1, 32);
    __syncthreads();
    float* ps = (float*)sm;
    if (lh == 0) { ps[w * 64 + l31] = s0; ps[w * 64 + 32 + l31] = s1; }
    __syncthreads();
    if (tid < 64) {
      float t = ps[tid] + ps[64 + tid] + ps[128 + tid] + ps[192 + tid];
      int tile = t0b >> 7;
      psum[((size_t)bh * NQT + tile) * DHEAD + tid] = t;
    }
  }
}

// ---------------- kernel 2: flash attention — LDS-free, barrier-free ---------
// One 64-thread wave per (bh, qt, 32-q slice). All MFMA fragments are
// contiguous 16B runs in global memory (K row-major, V transposed, Q row-major)
// -> direct global loads, zero LDS, zero __syncthreads. Multiplicative mask
// => logits ~N(0,1), static max 0, denominators additive; masked tail in
// closed form from psum suffix. P stays in-register via permlane32_swap.
// grid 3072: xcd = bid&7; per-XCD: qt descending (heavy first), bh pinned to
// one XCD so its 1MB K/V set stays in that XCD's L2.
__global__ __launch_bounds__(64, 3) void attn_k(
    const u16* __restrict__ qh, const u16* __restrict__ ql,
    const u16* __restrict__ kh, const u16* __restrict__ kl,
    const u16* __restrict__ vTh, const u16* __restrict__ vTl,
    const float* __restrict__ psum,
    u16* __restrict__ cxh, u16* __restrict__ cxl) {
  const int l = threadIdx.x;
  const int lh = l >> 5, l31 = l & 31;
  const int xcd = blockIdx.x & 7;
  const int idx = (int)blockIdx.x >> 3;          // 0..383
  const int qt = (NQT - 1) - (idx / 24);
  const int rem = idx % 24;
  const int bhl = rem >> 2, ws = rem & 3;
  const int bh = xcd * 6 + bhl;
  const int b = bh / NHEAD, h = bh % NHEAD;
  const int t0 = qt * QTILE;
  const size_t kvb = (size_t)bh * TSEQ * DHEAD;  // base for q/k rows AND vT

  // persistent Q B-frags: col q = l31 (this wave's 32-q slice), k = d
  const int qglo = t0 + 32 * ws;                 // first q row of this wave
  bf16x8 qfH[4], qfL[4];
#pragma unroll
  for (int ks = 0; ks < 4; ++ks) {
    size_t g = kvb + (size_t)(qglo + l31) * DHEAD + ks * 16 + 8 * lh;
    qfH[ks] = *(const bf16x8*)(qh + g);
    qfL[ks] = *(const bf16x8*)(ql + g);
  }

  f32x16 accO0, accO1;
#pragma unroll
  for (int i = 0; i < 16; ++i) { accO0[i] = 0.f; accO1[i] = 0.f; }
  float lrun = 0.f;
  const int qg = qglo + l31;
  const int S = 2 * (qt + 1);                    // 64-wide KV tiles to process

  for (int jt = 0; jt < S; ++jt) {
#pragma unroll
    for (int jh = 0; jh < 2; ++jh) {
      // ---- QK^T (split-3, 2 independent chains): S'[j][q], col q = l31
      f32x16 accSa, accSb;
#pragma unroll
      for (int i = 0; i < 16; ++i) { accSa[i] = 0.f; accSb[i] = 0.f; }
      const size_t krow = kvb + (size_t)(jt * 64 + jh * 32 + l31) * DHEAD;
      __builtin_amdgcn_s_setprio(1);
#pragma unroll
      for (int ks = 0; ks < 4; ++ks) {
        size_t g = krow + ks * 16 + 8 * lh;
        bf16x8 aH = *(const bf16x8*)(kh + g);
        bf16x8 aL = *(const bf16x8*)(kl + g);
        accSa = MFMA(aH, qfH[ks], accSa);
        accSb = MFMA(aH, qfL[ks], accSb);
        accSb = MFMA(aL, qfH[ks], accSb);
      }
      __builtin_amdgcn_s_setprio(0);
      f32x16 accS;
#pragma unroll
      for (int i = 0; i < 16; ++i) accS[i] = accSa[i] + accSb[i];

      // ---- mask (multiplicative: masked logits = 0), exp, sum, bf16 split
      const int jb = jt * 64 + jh * 32 + 4 * lh;
      float ps = 0.f;
#pragma unroll
      for (int ml = 0; ml < 2; ++ml) {
        int rb = ml * 8;
        u32 hw[4], lw[4];
#pragma unroll
        for (int pr = 0; pr < 4; ++pr) {
          int r0 = rb + 2 * pr;
          int jg0 = jb + (r0 & 3) + 8 * (r0 >> 2);
          float s0 = (jg0 > qg) ? 0.f : accS[r0];
          float s1 = ((jg0 + 1) > qg) ? 0.f : accS[r0 + 1];
          float p0 = __expf(s0), p1 = __expf(s1);
          ps += p0 + p1;
          u16 a0 = f2bf(p0), a1 = f2bf(p1);
          hw[pr] = (u32)a0 | ((u32)a1 << 16);
          lw[pr] = (u32)f2bf(p0 - bf2f(a0)) | ((u32)f2bf(p1 - bf2f(a1)) << 16);
        }
        // in-register P -> A-fragment redistribution (T12)
        i32x2 s1 = __builtin_amdgcn_permlane32_swap((int)hw[0], (int)hw[2], false, false);
        i32x2 s2 = __builtin_amdgcn_permlane32_swap((int)hw[1], (int)hw[3], false, false);
        bf16x8 pH = mk8((u32)s1.x, (u32)s2.x, (u32)s1.y, (u32)s2.y);
        i32x2 t1 = __builtin_amdgcn_permlane32_swap((int)lw[0], (int)lw[2], false, false);
        i32x2 t2 = __builtin_amdgcn_permlane32_swap((int)lw[1], (int)lw[3], false, false);
        bf16x8 pL = mk8((u32)t1.x, (u32)t2.x, (u32)t1.y, (u32)t2.y);
        // ---- PV (split-3): B-frags direct from vT[d][t]
        int m = jh * 2 + ml;                      // j = jt*64 + m*16 + 8lh + 0..7
        size_t vcol = (size_t)jt * 64 + m * 16 + 8 * lh;
        size_t v0 = kvb + (size_t)l31 * TSEQ + vcol;
        size_t v1 = kvb + (size_t)(32 + l31) * TSEQ + vcol;
        bf16x8 vH0 = *(const bf16x8*)(vTh + v0);
        bf16x8 vL0 = *(const bf16x8*)(vTl + v0);
        bf16x8 vH1 = *(const bf16x8*)(vTh + v1);
        bf16x8 vL1 = *(const bf16x8*)(vTl + v1);
        __builtin_amdgcn_s_setprio(1);
        accO0 = MFMA(pH, vH0, accO0); accO0 = MFMA(pH, vL0, accO0); accO0 = MFMA(pL, vH0, accO0);
        accO1 = MFMA(pH, vH1, accO1); accO1 = MFMA(pH, vL1, accO1); accO1 = MFMA(pL, vH1, accO1);
        __builtin_amdgcn_s_setprio(0);
      }
      lrun += ps;
    }
  }

  // ---- combine lane halves; closed-form masked tail (logit==0, weight 1)
  lrun += __shfl_xor(lrun, 32);
  lrun += (float)(TSEQ - S * 64);
  {
    float tl0 = 0.f, tl1 = 0.f;
    for (int tt = qt + 1; tt < NQT; ++tt) {
      const float* ps = psum + ((size_t)bh * NQT + tt) * DHEAD;
      tl0 += ps[l31];
      tl1 += ps[32 + l31];
    }
#pragma unroll
    for (int reg = 0; reg < 16; ++reg) { accO0[reg] += tl0; accO1[reg] += tl1; }
  }
  // ---- normalize + store ctx as bf16 hi/lo [b][t][h*64+d]
#pragma unroll
  for (int reg = 0; reg < 16; ++reg) {
    int qrow = (reg & 3) + 8 * (reg >> 2) + 4 * lh;
    float lq = __shfl(lrun, qrow);
    float inv = 1.f / lq;
    int t = qglo + qrow;
    size_t o = ((size_t)b * TSEQ + t) * EDIM + h * DHEAD;
    float v0 = accO0[reg] * inv, v1 = accO1[reg] * inv;
    u16 h0 = f2bf(v0), h1 = f2bf(v1);
    cxh[o + l31] = h0;       cxl[o + l31] = f2bf(v0 - bf2f(h0));
    cxh[o + 32 + l31] = h1;  cxl[o + 32 + l31] = f2bf(v1 - bf2f(h1));
  }
}

// ---------------- kernel 4: output projection --------------------------------
__global__ __launch_bounds__(256, 2) void outproj_k(
    const u16* __restrict__ cxh, const u16* __restrict__ cxl,
    const u16* __restrict__ woH, const u16* __restrict__ woL,
    float* __restrict__ out) {
  __shared__ __align__(16) unsigned char sm[32768];
  const int tid = threadIdx.x;
  const int w = tid >> 6, l = tid & 63, lh = l >> 5, l31 = l & 31;
  const int gid = ((blockIdx.x & 7) * 96) + ((int)blockIdx.x >> 3);
  const int bx = gid / 6, ey = gid % 6;
  const int bt0 = bx * 128, e0 = ey * 64;

  f32x16 acc0, acc1;
#pragma unroll
  for (int i = 0; i < 16; ++i) { acc0[i] = 0.f; acc1[i] = 0.f; }

  for (int k0 = 0; k0 < EDIM; k0 += 64) {
    __syncthreads();
#pragma unroll
    for (int i = 0; i < 4; ++i) {
      int c = tid + i * 256;
      int r = c >> 3, s = c & 7;
      int off = (r * 128 + s * 16) ^ ((r & 7) << 4);
      size_t g = (size_t)(bt0 + r) * EDIM + k0 + s * 8;
      *(uint4*)(sm + off) = *(const uint4*)(cxh + g);
      *(uint4*)(sm + 16384 + off) = *(const uint4*)(cxl + g);
    }
    __syncthreads();
    const int arow = 32 * w + l31;
#pragma unroll
    for (int ks = 0; ks < 4; ++ks) {
      int aoff = (arow * 128 + ks * 32 + 16 * lh) ^ ((arow & 7) << 4);
      bf16x8 aH = *(const bf16x8*)(sm + aoff);
      bf16x8 aL = *(const bf16x8*)(sm + 16384 + aoff);
      int hdoff = k0 + ks * 16 + 8 * lh;
      size_t b0 = (size_t)(e0 + l31) * EDIM + hdoff;
      size_t b1 = (size_t)(e0 + 32 + l31) * EDIM + hdoff;
      bf16x8 bH0 = *(const bf16x8*)(woH + b0);
      bf16x8 bL0 = *(const bf16x8*)(woL + b0);
      bf16x8 bH1 = *(const bf16x8*)(woH + b1);
      bf16x8 bL1 = *(const bf16x8*)(woL + b1);
      acc0 = MFMA(aH, bH0, acc0); acc0 = MFMA(aH, bL0, acc0); acc0 = MFMA(aL, bH0, acc0);
      acc1 = MFMA(aH, bH1, acc1); acc1 = MFMA(aH, bL1, acc1); acc1 = MFMA(aL, bH1, acc1);
    }
  }
#pragma unroll
  for (int reg = 0; reg < 16; ++reg) {
    int row = (reg & 3) + 8 * (reg >> 2) + 4 * lh + 32 * w;
    size_t o = (size_t)(bt0 + row) * EDIM + e0;
    out[o + l31] = acc0[reg];
    out[o + 32 + l31] = acc1[reg];
  }
}

// ---------------- launch -----------------------------------------------------
extern "C" void kernel_launch(void* const* d_in, const int* in_sizes, int n_in,
                              void* d_out, int out_size, void* d_ws, size_t ws_size,
                              hipStream_t stream) {
  (void)in_sizes; (void)n_in; (void)out_size; (void)ws_size;
  const float* x  = (const float*)d_in[0];
  const float* Wq = (const float*)d_in[1];
  const float* Wk = (const float*)d_in[2];
  const float* Wv = (const float*)d_in[3];
  const float* Wo = (const float*)d_in[4];
  float* out = (float*)d_out;

  // workspace carve (~104 MB)
  u16* qh  = (u16*)d_ws;
  u16* ql  = qh + KVSZ;
  u16* kh  = ql + KVSZ;
  u16* kl  = kh + KVSZ;
  u16* vTh = kl + KVSZ;
  u16* vTl = vTh + KVSZ;
  u16* xh  = vTl + KVSZ;
  u16* xl  = xh + XSZ;
  u16* wtH = xl + XSZ;
  u16* wtL = wtH + NW1;
  u16* woH = wtL + NW1;
  u16* woL = woH + NW2;
  float* psum = (float*)(woL + NW2);     // 48*16*64 fp32
  u16* cxh = xh;   // alias: x dead after proj
  u16* cxl = xl;

  hipLaunchKernelGGL(prep_w_k, dim3((NW1 + NW2) / 256), dim3(256), 0, stream,
                     Wq, Wk, Wv, Wo, wtH, wtL, woH, woL);
  hipLaunchKernelGGL(splitx_k, dim3(XSZ / 2048), dim3(256), 0, stream, x, xh, xl);
  hipLaunchKernelGGL(proj_k, dim3(2304), dim3(256), 0, stream,
                     xh, xl, wtH, wtL, qh, ql, kh, kl, vTh, vTl, psum);
  hipLaunchKernelGGL(attn_k, dim3(3072), dim3(64), 0, stream,
                     qh, ql, kh, kl, vTh, vTl, psum, cxh, cxl);
  hipLaunchKernelGGL(outproj_k, dim3(768), dim3(256), 0, stream,
                     cxh, cxl, woH, woL, out);
}

// Round 8
// 452.819 us; speedup vs baseline: 1.2173x; 1.0172x over previous
//
#include <hip/hip_runtime.h>
#include <hip/hip_bf16.h>
#include <math.h>

#define BBATCH 8
#define TSEQ   2048
#define EDIM   384
#define NHEAD  6
#define DHEAD  64
#define NBH    48
#define QTILE  128
#define NQT    16
#define NW1    442368          // 3*6*64*384
#define NW2    147456          // 384*384
#define XSZ    6291456         // B*T*E
#define KVSZ   6291456         // NBH*T*HS

typedef __attribute__((ext_vector_type(8)))  short bf16x8;
typedef __attribute__((ext_vector_type(16))) float f32x16;
typedef __attribute__((ext_vector_type(2)))  int   i32x2;
typedef unsigned short u16;
typedef unsigned int   u32;

#define MFMA(a, b, c) __builtin_amdgcn_mfma_f32_32x32x16_bf16(a, b, c, 0, 0, 0)

__device__ __forceinline__ u16 f2bf(float f) {
  u32 u = __float_as_uint(f);
  return (u16)((u + 0x7fffu + ((u >> 16) & 1u)) >> 16);
}
__device__ __forceinline__ float bf2f(u16 h) {
  return __uint_as_float(((u32)h) << 16);
}
// packed RNE f32x2 -> bf16x2 (compiler emits v_cvt_pk_bf16_f32); .x -> low bits
__device__ __forceinline__ u32 pk2(float a, float b) {
  __hip_bfloat162 t = __float22bfloat162_rn(make_float2(a, b));
  union { __hip_bfloat162 v; u32 u; } c; c.v = t; return c.u;
}
__device__ __forceinline__ bf16x8 mk8(u32 w0, u32 w1, u32 w2, u32 w3) {
  union { u32 u[4]; bf16x8 v; } t;
  t.u[0] = w0; t.u[1] = w1; t.u[2] = w2; t.u[3] = w3;
  return t.v;
}

// ---------------- kernel 0a: weight prep (transpose + hi/lo split) -----------
__global__ __launch_bounds__(256) void prep_w_k(
    const float* __restrict__ Wq, const float* __restrict__ Wk,
    const float* __restrict__ Wv, const float* __restrict__ Wo,
    u16* __restrict__ wtH, u16* __restrict__ wtL,
    u16* __restrict__ woH, u16* __restrict__ woL) {
  int idx = blockIdx.x * 256 + threadIdx.x;
  if (idx < NW1) {
    int d = idx & 63;
    int q = idx >> 6;
    int e = q % EDIM;
    int ph = q / EDIM;
    const float* W = (ph < 6) ? Wq : (ph < 12) ? Wk : Wv;
    int h = ph % 6;
    float v = W[((size_t)h * EDIM + e) * DHEAD + d];
    u16 hi = f2bf(v);
    size_t o = ((size_t)ph * DHEAD + d) * EDIM + e;
    wtH[o] = hi;
    wtL[o] = f2bf(v - bf2f(hi));
  } else {
    int o = idx - NW1;
    int eo = o % EDIM;
    int hd = o / EDIM;
    float v = Wo[(size_t)hd * EDIM + eo];
    u16 hi = f2bf(v);
    size_t oo = (size_t)eo * EDIM + hd;
    woH[oo] = hi;
    woL[oo] = f2bf(v - bf2f(hi));
  }
}

// ---------------- kernel 0b: pre-split x into bf16 hi/lo ---------------------
__global__ __launch_bounds__(256) void splitx_k(
    const float* __restrict__ x, u16* __restrict__ xh, u16* __restrict__ xl) {
  int i = (blockIdx.x * 256 + threadIdx.x) * 8;
  float4 a = *(const float4*)(x + i);
  float4 b = *(const float4*)(x + i + 4);
  u16 h0 = f2bf(a.x), h1 = f2bf(a.y), h2 = f2bf(a.z), h3 = f2bf(a.w);
  u16 h4 = f2bf(b.x), h5 = f2bf(b.y), h6 = f2bf(b.z), h7 = f2bf(b.w);
  uint4 H, L;
  H.x = (u32)h0 | ((u32)h1 << 16); H.y = (u32)h2 | ((u32)h3 << 16);
  H.z = (u32)h4 | ((u32)h5 << 16); H.w = (u32)h6 | ((u32)h7 << 16);
  L.x = (u32)f2bf(a.x - bf2f(h0)) | ((u32)f2bf(a.y - bf2f(h1)) << 16);
  L.y = (u32)f2bf(a.z - bf2f(h2)) | ((u32)f2bf(a.w - bf2f(h3)) << 16);
  L.z = (u32)f2bf(b.x - bf2f(h4)) | ((u32)f2bf(b.y - bf2f(h5)) << 16);
  L.w = (u32)f2bf(b.z - bf2f(h6)) | ((u32)f2bf(b.w - bf2f(h7)) << 16);
  *(uint4*)(xh + i) = H;
  *(uint4*)(xl + i) = L;
}

// ---------------- kernel 1: Q/K/V projection (split-bf16 MFMA) ---------------
// V path additionally emits psum[bh][tile][d] = sum over the 128 rows (fp32).
__global__ __launch_bounds__(256, 4) void proj_k(
    const u16* __restrict__ xh, const u16* __restrict__ xl,
    const u16* __restrict__ wtH, const u16* __restrict__ wtL,
    u16* __restrict__ qh, u16* __restrict__ ql,
    u16* __restrict__ kh, u16* __restrict__ kl,
    u16* __restrict__ vTh, u16* __restrict__ vTl,
    float* __restrict__ psum) {
  __shared__ __align__(16) unsigned char sm[32768];
  const int tid = threadIdx.x;
  const int w = tid >> 6, l = tid & 63, lh = l >> 5, l31 = l & 31;
  const int gid = ((blockIdx.x & 7) * 288) + ((int)blockIdx.x >> 3);
  const int bx = gid / 18, ph = gid % 18;
  const int p = ph / 6, h = ph % 6;
  const int bt0 = bx * 128;
  const u16* __restrict__ wBh = wtH + (size_t)ph * DHEAD * EDIM;
  const u16* __restrict__ wBl = wtL + (size_t)ph * DHEAD * EDIM;

  f32x16 acc0, acc1;
#pragma unroll
  for (int i = 0; i < 16; ++i) { acc0[i] = 0.f; acc1[i] = 0.f; }

  for (int k0 = 0; k0 < EDIM; k0 += 64) {
    __syncthreads();
#pragma unroll
    for (int i = 0; i < 4; ++i) {
      int c = tid + i * 256;
      int r = c >> 3, s = c & 7;
      int off = (r * 128 + s * 16) ^ ((r & 7) << 4);
      size_t g = (size_t)(bt0 + r) * EDIM + k0 + s * 8;
      *(uint4*)(sm + off) = *(const uint4*)(xh + g);
      *(uint4*)(sm + 16384 + off) = *(const uint4*)(xl + g);
    }
    __syncthreads();
    const int arow = 32 * w + l31;
#pragma unroll
    for (int ks = 0; ks < 4; ++ks) {
      int aoff = (arow * 128 + ks * 32 + 16 * lh) ^ ((arow & 7) << 4);
      bf16x8 aH = *(const bf16x8*)(sm + aoff);
      bf16x8 aL = *(const bf16x8*)(sm + 16384 + aoff);
      int eoff = k0 + ks * 16 + 8 * lh;
      size_t b0 = (size_t)l31 * EDIM + eoff;
      size_t b1 = (size_t)(32 + l31) * EDIM + eoff;
      bf16x8 bH0 = *(const bf16x8*)(wBh + b0);
      bf16x8 bL0 = *(const bf16x8*)(wBl + b0);
      bf16x8 bH1 = *(const bf16x8*)(wBh + b1);
      bf16x8 bL1 = *(const bf16x8*)(wBl + b1);
      acc0 = MFMA(aH, bH0, acc0); acc0 = MFMA(aH, bL0, acc0); acc0 = MFMA(aL, bH0, acc0);
      acc1 = MFMA(aH, bH1, acc1); acc1 = MFMA(aH, bL1, acc1); acc1 = MFMA(aL, bH1, acc1);
    }
  }

  const int b = bt0 >> 11, t0b = bt0 & (TSEQ - 1);
  const int bh = b * NHEAD + h;
  const float scale = (p == 0) ? 0.125f : 1.0f;

  if (p < 2) {
    u16* oH = (p == 0) ? qh : kh;
    u16* oL = (p == 0) ? ql : kl;
#pragma unroll
    for (int reg = 0; reg < 16; ++reg) {
      int row = (reg & 3) + 8 * (reg >> 2) + 4 * lh + 32 * w;
      size_t base = ((size_t)bh * TSEQ + t0b + row) * DHEAD;
      float v0 = acc0[reg] * scale, v1 = acc1[reg] * scale;
      u16 h0 = f2bf(v0), h1 = f2bf(v1);
      oH[base + l31] = h0;       oL[base + l31] = f2bf(v0 - bf2f(h0));
      oH[base + 32 + l31] = h1;  oL[base + 32 + l31] = f2bf(v1 - bf2f(h1));
    }
  } else {
    // V: transpose via LDS -> vT[bh][d][t]
    u16* T = (u16*)sm;
#pragma unroll
    for (int half = 0; half < 2; ++half) {
      __syncthreads();
#pragma unroll
      for (int reg = 0; reg < 16; ++reg) {
        int t = (reg & 3) + 8 * (reg >> 2) + 4 * lh + 32 * w;
        float v0 = acc0[reg], v1 = acc1[reg];
        u16 e0, e1;
        if (half == 0) { e0 = f2bf(v0); e1 = f2bf(v1); }
        else {
          u16 a0 = f2bf(v0), a1 = f2bf(v1);
          e0 = f2bf(v0 - bf2f(a0)); e1 = f2bf(v1 - bf2f(a1));
        }
        T[l31 * 132 + t] = e0;
        T[(32 + l31) * 132 + t] = e1;
      }
      __syncthreads();
      u16* dst = half ? vTl : vTh;
#pragma unroll
      for (int i = 0; i < 8; ++i) {
        int c = tid + i * 256;
        int d = c >> 5, s = c & 31;
        uint2 val = *(const uint2*)(T + d * 132 + s * 4);
        *(uint2*)(dst + ((size_t)bh * DHEAD + d) * TSEQ + t0b + s * 4) = val;
      }
    }
    // per-tile V column sums (fp32) for the masked-tail closed form
    float s0 = 0.f, s1 = 0.f;
#pragma unroll
    for (int reg = 0; reg < 16; ++reg) { s0 += acc0[reg]; s1 += acc1[reg]; }
    s0 += __shfl_xor(s0, 32);
    s1 += __shfl_xor(s1, 32);
    __syncthreads();
    float* ps = (float*)sm;
    if (lh == 0) { ps[w * 64 + l31] = s0; ps[w * 64 + 32 + l31] = s1; }
    __syncthreads();
    if (tid < 64) {
      float t = ps[tid] + ps[64 + tid] + ps[128 + tid] + ps[192 + tid];
      int tile = t0b >> 7;
      psum[((size_t)bh * NQT + tile) * DHEAD + tid] = t;
    }
  }
}

// ---------------- kernel 2: flash attention — LDS-free, software-pipelined ---
// One 64-thread wave per (bh, qt, 32-q slice); zero LDS / zero barriers.
// Register double-buffered K (prefetch next 32-row step while computing this
// one); V loads issue right after QK and drain under softmax (T14). P stays
// in-register via permlane32_swap; P hi/lo split via packed cvt (pk2).
// Multiplicative mask => static max 0, additive denominators; masked tail in
// closed form from psum suffix.
#define LOADK(DST, S_) do {                                                  \
    size_t ldk_g = kvb + (size_t)((S_) * 32 + l31) * DHEAD + 8 * lh;         \
    DST[0] = *(const bf16x8*)(kh + ldk_g);                                   \
    DST[1] = *(const bf16x8*)(kh + ldk_g + 16);                              \
    DST[2] = *(const bf16x8*)(kh + ldk_g + 32);                              \
    DST[3] = *(const bf16x8*)(kh + ldk_g + 48);                              \
    DST[4] = *(const bf16x8*)(kl + ldk_g);                                   \
    DST[5] = *(const bf16x8*)(kl + ldk_g + 16);                              \
    DST[6] = *(const bf16x8*)(kl + ldk_g + 32);                              \
    DST[7] = *(const bf16x8*)(kl + ldk_g + 48);                              \
  } while (0)

#define STEP(CUR, NXT, S_) do {                                              \
    const int st_ = (S_);                                                    \
    LOADK(NXT, (st_ + 1 < smax2) ? st_ + 1 : smax2 - 1);                     \
    f32x16 aSa, aSb;                                                         \
    _Pragma("unroll")                                                        \
    for (int i_ = 0; i_ < 16; ++i_) { aSa[i_] = 0.f; aSb[i_] = 0.f; }        \
    __builtin_amdgcn_s_setprio(1);                                           \
    aSa = MFMA(CUR[0], qfH[0], aSa); aSb = MFMA(CUR[0], qfL[0], aSb);        \
    aSb = MFMA(CUR[4], qfH[0], aSb);                                         \
    aSa = MFMA(CUR[1], qfH[1], aSa); aSb = MFMA(CUR[1], qfL[1], aSb);        \
    aSb = MFMA(CUR[5], qfH[1], aSb);                                         \
    aSa = MFMA(CUR[2], qfH[2], aSa); aSb = MFMA(CUR[2], qfL[2], aSb);        \
    aSb = MFMA(CUR[6], qfH[2], aSb);                                         \
    aSa = MFMA(CUR[3], qfH[3], aSa); aSb = MFMA(CUR[3], qfL[3], aSb);        \
    aSb = MFMA(CUR[7], qfH[3], aSb);                                         \
    __builtin_amdgcn_s_setprio(0);                                           \
    size_t vr0_ = kvb + (size_t)l31 * TSEQ + (size_t)st_ * 32 + 8 * lh;      \
    size_t vr1_ = vr0_ + (size_t)32 * TSEQ;                                  \
    bf16x8 v0H0 = *(const bf16x8*)(vTh + vr0_);                              \
    bf16x8 v0L0 = *(const bf16x8*)(vTl + vr0_);                              \
    bf16x8 v1H0 = *(const bf16x8*)(vTh + vr1_);                              \
    bf16x8 v1L0 = *(const bf16x8*)(vTl + vr1_);                              \
    bf16x8 v0H1 = *(const bf16x8*)(vTh + vr0_ + 16);                         \
    bf16x8 v0L1 = *(const bf16x8*)(vTl + vr0_ + 16);                         \
    bf16x8 v1H1 = *(const bf16x8*)(vTh + vr1_ + 16);                         \
    bf16x8 v1L1 = *(const bf16x8*)(vTl + vr1_ + 16);                         \
    f32x16 accS_;                                                            \
    _Pragma("unroll")                                                        \
    for (int i_ = 0; i_ < 16; ++i_) accS_[i_] = aSa[i_] + aSb[i_];           \
    const int jb_ = st_ * 32 + 4 * lh;                                       \
    float ps_ = 0.f;                                                         \
    _Pragma("unroll")                                                        \
    for (int ml_ = 0; ml_ < 2; ++ml_) {                                      \
      u32 hw_[4], lw_[4];                                                    \
      _Pragma("unroll")                                                      \
      for (int pr_ = 0; pr_ < 4; ++pr_) {                                    \
        int r0_ = ml_ * 8 + 2 * pr_;                                         \
        int jg_ = jb_ + (r0_ & 3) + 8 * (r0_ >> 2);                          \
        float s0_ = (jg_ > qg) ? 0.f : accS_[r0_];                           \
        float s1_ = (jg_ + 1 > qg) ? 0.f : accS_[r0_ + 1];                   \
        float p0_ = __expf(s0_), p1_ = __expf(s1_);                          \
        ps_ += p0_ + p1_;                                                    \
        u32 w_ = pk2(p0_, p1_);                                              \
        hw_[pr_] = w_;                                                       \
        lw_[pr_] = pk2(p0_ - __uint_as_float(w_ << 16),                      \
                       p1_ - __uint_as_float(w_ & 0xffff0000u));             \
      }                                                                      \
      i32x2 sA_ = __builtin_amdgcn_permlane32_swap((int)hw_[0], (int)hw_[2], false, false); \
      i32x2 sB_ = __builtin_amdgcn_permlane32_swap((int)hw_[1], (int)hw_[3], false, false); \
      bf16x8 pH_ = mk8((u32)sA_.x, (u32)sB_.x, (u32)sA_.y, (u32)sB_.y);      \
      i32x2 tA_ = __builtin_amdgcn_permlane32_swap((int)lw_[0], (int)lw_[2], false, false); \
      i32x2 tB_ = __builtin_amdgcn_permlane32_swap((int)lw_[1], (int)lw_[3], false, false); \
      bf16x8 pL_ = mk8((u32)tA_.x, (u32)tB_.x, (u32)tA_.y, (u32)tB_.y);      \
      bf16x8 vh0_ = ml_ ? v0H1 : v0H0;                                       \
      bf16x8 vl0_ = ml_ ? v0L1 : v0L0;                                       \
      bf16x8 vh1_ = ml_ ? v1H1 : v1H0;                                       \
      bf16x8 vl1_ = ml_ ? v1L1 : v1L0;                                       \
      __builtin_amdgcn_s_setprio(1);                                         \
      accO0 = MFMA(pH_, vh0_, accO0); accO0 = MFMA(pH_, vl0_, accO0);        \
      accO0 = MFMA(pL_, vh0_, accO0);                                        \
      accO1 = MFMA(pH_, vh1_, accO1); accO1 = MFMA(pH_, vl1_, accO1);        \
      accO1 = MFMA(pL_, vh1_, accO1);                                        \
      __builtin_amdgcn_s_setprio(0);                                         \
    }                                                                        \
    lrun += ps_;                                                             \
  } while (0)

__global__ __launch_bounds__(64, 2) void attn_k(
    const u16* __restrict__ qh, const u16* __restrict__ ql,
    const u16* __restrict__ kh, const u16* __restrict__ kl,
    const u16* __restrict__ vTh, const u16* __restrict__ vTl,
    const float* __restrict__ psum,
    u16* __restrict__ cxh, u16* __restrict__ cxl) {
  const int l = threadIdx.x;
  const int lh = l >> 5, l31 = l & 31;
  const int xcd = blockIdx.x & 7;
  const int idx = (int)blockIdx.x >> 3;          // 0..383
  const int qt = (NQT - 1) - (idx / 24);
  const int rem = idx % 24;
  const int bhl = rem >> 2, ws = rem & 3;
  const int bh = xcd * 6 + bhl;
  const int b = bh / NHEAD, h = bh % NHEAD;
  const size_t kvb = (size_t)bh * TSEQ * DHEAD;

  // persistent Q B-frags: col q = l31 of this wave's 32-q slice
  const int qglo = qt * QTILE + 32 * ws;
  bf16x8 qfH[4], qfL[4];
#pragma unroll
  for (int ks = 0; ks < 4; ++ks) {
    size_t g = kvb + (size_t)(qglo + l31) * DHEAD + ks * 16 + 8 * lh;
    qfH[ks] = *(const bf16x8*)(qh + g);
    qfL[ks] = *(const bf16x8*)(ql + g);
  }

  f32x16 accO0, accO1;
#pragma unroll
  for (int i = 0; i < 16; ++i) { accO0[i] = 0.f; accO1[i] = 0.f; }
  float lrun = 0.f;
  const int qg = qglo + l31;
  const int smax2 = 4 * (qt + 1);                // 32-row steps (always even)

  bf16x8 KA[8], KB[8];
  LOADK(KA, 0);

  for (int s = 0; s < smax2; s += 2) {
    STEP(KA, KB, s);
    STEP(KB, KA, s + 1);
  }

  // combine lane halves; closed-form masked tail (logit==0, weight 1)
  lrun += __shfl_xor(lrun, 32);
  lrun += (float)(TSEQ - smax2 * 32);
  {
    float tl0 = 0.f, tl1 = 0.f;
    for (int tt = qt + 1; tt < NQT; ++tt) {
      const float* ps = psum + ((size_t)bh * NQT + tt) * DHEAD;
      tl0 += ps[l31];
      tl1 += ps[32 + l31];
    }
#pragma unroll
    for (int reg = 0; reg < 16; ++reg) { accO0[reg] += tl0; accO1[reg] += tl1; }
  }
  // normalize + store ctx as bf16 hi/lo [b][t][h*64+d]
#pragma unroll
  for (int reg = 0; reg < 16; ++reg) {
    int qrow = (reg & 3) + 8 * (reg >> 2) + 4 * lh;
    float lq = __shfl(lrun, qrow);
    float inv = 1.f / lq;
    int t = qglo + qrow;
    size_t o = ((size_t)b * TSEQ + t) * EDIM + h * DHEAD;
    float v0 = accO0[reg] * inv, v1 = accO1[reg] * inv;
    u16 h0 = f2bf(v0), h1 = f2bf(v1);
    cxh[o + l31] = h0;       cxl[o + l31] = f2bf(v0 - bf2f(h0));
    cxh[o + 32 + l31] = h1;  cxl[o + 32 + l31] = f2bf(v1 - bf2f(h1));
  }
}
#undef STEP
#undef LOADK

// ---------------- kernel 4: output projection --------------------------------
__global__ __launch_bounds__(256, 4) void outproj_k(
    const u16* __restrict__ cxh, const u16* __restrict__ cxl,
    const u16* __restrict__ woH, const u16* __restrict__ woL,
    float* __restrict__ out) {
  __shared__ __align__(16) unsigned char sm[32768];
  const int tid = threadIdx.x;
  const int w = tid >> 6, l = tid & 63, lh = l >> 5, l31 = l & 31;
  const int gid = ((blockIdx.x & 7) * 96) + ((int)blockIdx.x >> 3);
  const int bx = gid / 6, ey = gid % 6;
  const int bt0 = bx * 128, e0 = ey * 64;

  f32x16 acc0, acc1;
#pragma unroll
  for (int i = 0; i < 16; ++i) { acc0[i] = 0.f; acc1[i] = 0.f; }

  for (int k0 = 0; k0 < EDIM; k0 += 64) {
    __syncthreads();
#pragma unroll
    for (int i = 0; i < 4; ++i) {
      int c = tid + i * 256;
      int r = c >> 3, s = c & 7;
      int off = (r * 128 + s * 16) ^ ((r & 7) << 4);
      size_t g = (size_t)(bt0 + r) * EDIM + k0 + s * 8;
      *(uint4*)(sm + off) = *(const uint4*)(cxh + g);
      *(uint4*)(sm + 16384 + off) = *(const uint4*)(cxl + g);
    }
    __syncthreads();
    const int arow = 32 * w + l31;
#pragma unroll
    for (int ks = 0; ks < 4; ++ks) {
      int aoff = (arow * 128 + ks * 32 + 16 * lh) ^ ((arow & 7) << 4);
      bf16x8 aH = *(const bf16x8*)(sm + aoff);
      bf16x8 aL = *(const bf16x8*)(sm + 16384 + aoff);
      int hdoff = k0 + ks * 16 + 8 * lh;
      size_t b0 = (size_t)(e0 + l31) * EDIM + hdoff;
      size_t b1 = (size_t)(e0 + 32 + l31) * EDIM + hdoff;
      bf16x8 bH0 = *(const bf16x8*)(woH + b0);
      bf16x8 bL0 = *(const bf16x8*)(woL + b0);
      bf16x8 bH1 = *(const bf16x8*)(woH + b1);
      bf16x8 bL1 = *(const bf16x8*)(woL + b1);
      acc0 = MFMA(aH, bH0, acc0); acc0 = MFMA(aH, bL0, acc0); acc0 = MFMA(aL, bH0, acc0);
      acc1 = MFMA(aH, bH1, acc1); acc1 = MFMA(aH, bL1, acc1); acc1 = MFMA(aL, bH1, acc1);
    }
  }
#pragma unroll
  for (int reg = 0; reg < 16; ++reg) {
    int row = (reg & 3) + 8 * (reg >> 2) + 4 * lh + 32 * w;
    size_t o = (size_t)(bt0 + row) * EDIM + e0;
    out[o + l31] = acc0[reg];
    out[o + 32 + l31] = acc1[reg];
  }
}

// ---------------- launch -----------------------------------------------------
extern "C" void kernel_launch(void* const* d_in, const int* in_sizes, int n_in,
                              void* d_out, int out_size, void* d_ws, size_t ws_size,
                              hipStream_t stream) {
  (void)in_sizes; (void)n_in; (void)out_size; (void)ws_size;
  const float* x  = (const float*)d_in[0];
  const float* Wq = (const float*)d_in[1];
  const float* Wk = (const float*)d_in[2];
  const float* Wv = (const float*)d_in[3];
  const float* Wo = (const float*)d_in[4];
  float* out = (float*)d_out;

  // workspace carve (~104 MB)
  u16* qh  = (u16*)d_ws;
  u16* ql  = qh + KVSZ;
  u16* kh  = ql + KVSZ;
  u16* kl  = kh + KVSZ;
  u16* vTh = kl + KVSZ;
  u16* vTl = vTh + KVSZ;
  u16* xh  = vTl + KVSZ;
  u16* xl  = xh + XSZ;
  u16* wtH = xl + XSZ;
  u16* wtL = wtH + NW1;
  u16* woH = wtL + NW1;
  u16* woL = woH + NW2;
  float* psum = (float*)(woL + NW2);     // 48*16*64 fp32
  u16* cxh = xh;   // alias: x dead after proj
  u16* cxl = xl;

  hipLaunchKernelGGL(prep_w_k, dim3((NW1 + NW2) / 256), dim3(256), 0, stream,
                     Wq, Wk, Wv, Wo, wtH, wtL, woH, woL);
  hipLaunchKernelGGL(splitx_k, dim3(XSZ / 2048), dim3(256), 0, stream, x, xh, xl);
  hipLaunchKernelGGL(proj_k, dim3(2304), dim3(256), 0, stream,
                     xh, xl, wtH, wtL, qh, ql, kh, kl, vTh, vTl, psum);
  hipLaunchKernelGGL(attn_k, dim3(3072), dim3(64), 0, stream,
                     qh, ql, kh, kl, vTh, vTl, psum, cxh, cxl);
  hipLaunchKernelGGL(outproj_k, dim3(768), dim3(256), 0, stream,
                     cxh, cxl, woH, woL, out);
}